// Round 3
// baseline (285.561 us; speedup 1.0000x reference)
//
#include <hip/hip_runtime.h>

#define NUM_NET 2
#define V 100000
#define D 128
#define B 4096
#define K 5
#define NS 10

// weight magnitudes (sign encoded separately in the 3-bit code)
#define W_MAIN_POS (1.0f/20480.0f)   // 1/(B*K)
#define W_INV_B    (1.0f/4096.0f)    // 1/B
#define HYP_B      (0.1f/4096.0f)    // HYP{1,2,3}/B (all 0.1)
#define HYP2_BK    (0.1f/20480.0f)   // HYP2/(B*K)

// packed entry: idx[0:19] | tab[20:21] | code[22:24]
// code: 0=+W_MAIN_POS  3=-W_INV_B  4=+HYP_B  5=-HYP_B  6=+HYP2_BK  7=pad(0)
// sign = code&1 (codes 3,5,7 negative; 7 has mag 0 so sign irrelevant)

__global__ __launch_bounds__(256, 8) void rmne_main(
    const float* __restrict__ node_tables,
    const float* __restrict__ neigh_tables,
    const int*   __restrict__ nodes_idx,
    const int*   __restrict__ neigh_idx,
    const int*   __restrict__ role_idx,
    const int*   __restrict__ neg_main,
    const int*   __restrict__ neg_node,
    const int*   __restrict__ neg_cross,
    const int*   __restrict__ neg_role,
    float*       __restrict__ out)
{
    const int tid  = threadIdx.x;
    const int lane = tid & 63;
    const int wave = tid >> 6;
    const int unit = blockIdx.x * 4 + wave;   // 8192 units
    const int i = unit >> 12;                 // net index (0/1)
    const int b = unit & (B - 1);
    const int j = 1 - i;

    // ---- build the 144-entry dot list; entry d at lane d&63, slot d>>6 ----
    int pk[3];
    #pragma unroll
    for (int s = 0; s < 3; ++s) {
        int d = lane + 64 * s;
        int idx = 0, tab = 0, code = 7;
        if      (d <   5) { idx = neigh_idx[(i*B + b)*K + d];              tab = 2 + i; code = 0; }
        else if (d <  55) { idx = neg_main[(i*B + b)*50 + (d-5)];          tab = 2 + i; code = 3; }
        else if (d <  56) { idx = nodes_idx[i*B + b];                      tab = j;     code = 4; }
        else if (d <  66) { idx = neg_node[((i*2+j)*B + b)*NS + (d-56)];   tab = j;     code = 5; }
        else if (d <  71) { idx = neigh_idx[(i*B + b)*K + (d-66)];         tab = 2 + j; code = 6; }
        else if (d < 121) { idx = neg_cross[((i*2+j)*B + b)*50 + (d-71)];  tab = 2 + j; code = 5; }
        else if (d < 122) { idx = role_idx[(i*2+0)*B + b];                 tab = 0;     code = 4; }
        else if (d < 132) { idx = neg_role[((i*2+0)*B + b)*NS + (d-122)];  tab = 0;     code = 5; }
        else if (d < 133) { idx = role_idx[(i*2+1)*B + b];                 tab = 1;     code = 4; }
        else if (d < 143) { idx = neg_role[((i*2+1)*B + b)*NS + (d-133)];  tab = 1;     code = 5; }
        pk[s] = idx | (tab << 20) | (code << 22);
    }

    // ---- node embedding fragment: quarter-wave layout, 8 dims/lane ----
    const int l16     = lane & 15;
    const int quarter = lane >> 4;
    const int nrow    = nodes_idx[i*B + b];
    const float4* nrp = (const float4*)(node_tables + ((size_t)i*V + (size_t)nrow)*D) + l16*2;
    const float4 ne0 = nrp[0];
    const float4 ne1 = nrp[1];

    float acc = 0.0f;

    // depth-2 pipeline registers: cur (compute), mid (in flight), nxt (issuing)
    int e_cur, e_mid, e_nxt;
    float4 cc0, cc1, m0, m1, n0, n1;

    auto rowload = [&](int e, float4& r0, float4& r1) {
        int idx = e & 0xFFFFF;
        int tab = (e >> 20) & 3;
        const float* base = (tab & 2) ? neigh_tables : node_tables;
        const float4* row = (const float4*)(base + ((size_t)(tab & 1)*V + (size_t)idx)*D) + l16*2;
        r0 = row[0];
        r1 = row[1];
    };

    auto compute = [&]() {
        float pp = ne0.x*cc0.x + ne0.y*cc0.y + ne0.z*cc0.z + ne0.w*cc0.w
                 + ne1.x*cc1.x + ne1.y*cc1.y + ne1.z*cc1.z + ne1.w*cc1.w;
        pp += __shfl_xor(pp, 1, 64);
        pp += __shfl_xor(pp, 2, 64);
        pp += __shfl_xor(pp, 4, 64);
        pp += __shfl_xor(pp, 8, 64);
        int code = (e_cur >> 22) & 7;
        float mag = (code == 0) ? W_MAIN_POS
                  : (code == 3) ? W_INV_B
                  : (code == 6) ? HYP2_BK
                  : (code == 7) ? 0.0f
                  : HYP_B;
        float x  = (code & 1) ? -pp : pp;
        float ls = fminf(x, 0.0f) - __logf(1.0f + __expf(-fabsf(x)));
        acc += mag * ls;
    };

    auto rotate = [&]() {
        e_cur = e_mid; cc0 = m0; cc1 = m1;
        e_mid = e_nxt; m0  = n0; m1  = n1;
    };

    // prologue: entries 0 and 1 (both slot 0; lane = 4t+quarter)
    e_cur = __shfl(pk[0], quarter, 64);
    rowload(e_cur, cc0, cc1);
    e_mid = __shfl(pk[0], 4 + quarter, 64);
    rowload(e_mid, m0, m1);

    // steady state: step tn prefetches entry tn, computes entry tn-2
    auto step = [&](int tn, int slotpk) {
        e_nxt = __shfl(slotpk, (4*tn + quarter) & 63, 64);
        rowload(e_nxt, n0, n1);
        compute();
        rotate();
    };

    #pragma unroll 4
    for (int tn = 2;  tn < 16; ++tn) step(tn, pk[0]);
    #pragma unroll 4
    for (int tn = 16; tn < 32; ++tn) step(tn, pk[1]);
    #pragma unroll
    for (int tn = 32; tn < 36; ++tn) step(tn, pk[2]);

    // epilogue: entries 34 and 35
    compute();
    e_cur = e_mid; cc0 = m0; cc1 = m1;
    compute();

    // acc replicated within each quarter; add one representative per quarter
    acc += __shfl_xor(acc, 16, 64);
    acc += __shfl_xor(acc, 32, 64);

    __shared__ float wsum[4];
    if (lane == 0) wsum[wave] = acc;
    __syncthreads();
    if (tid == 0) {
        float s = wsum[0] + wsum[1] + wsum[2] + wsum[3];
        atomicAdd(out, s * (-1.0f / 10.0f));
    }
}

extern "C" void kernel_launch(void* const* d_in, const int* in_sizes, int n_in,
                              void* d_out, int out_size, void* d_ws, size_t ws_size,
                              hipStream_t stream) {
    const float* node_tables  = (const float*)d_in[0];
    const float* neigh_tables = (const float*)d_in[1];
    const int*   nodes_idx    = (const int*)d_in[2];
    const int*   neigh_idx    = (const int*)d_in[3];
    const int*   role_idx     = (const int*)d_in[4];
    const int*   neg_main     = (const int*)d_in[5];
    const int*   neg_node     = (const int*)d_in[6];
    const int*   neg_cross    = (const int*)d_in[7];
    const int*   neg_role     = (const int*)d_in[8];
    float* out = (float*)d_out;

    hipMemsetAsync(out, 0, sizeof(float), stream);
    rmne_main<<<2048, 256, 0, stream>>>(node_tables, neigh_tables, nodes_idx, neigh_idx,
                                        role_idx, neg_main, neg_node, neg_cross, neg_role, out);
}